// Round 14
// baseline (232.246 us; speedup 1.0000x reference)
//
#include <hip/hip_runtime.h>
#include <stdint.h>

// Quant3Linear GEMV: y = x @ (scales.T * unpack3(qweight) - zeros.T) + bias
//   x: (1, 8192) f32 | qweight: (768, 28672) i32 | scales,zeros: (28672,1) | bias: (28672,)
// Decomposition: y[o] = scales[o]*dot(x, q[:,o]) - zeros[o]*sum(x) + bias[o]
//
// R14: MEASUREMENT ROUND 3 -- R13's SGPR-x scalar-magic kernel, byte-identical
// body, amplified 5x via blockIdx.z (z<4 -> dummy in d_ws, z==4 -> real out;
// R11's proven mechanism) to push it past the 51us fill cutoff and get its
// OWN counters. Motivation: five dot restructures (cvt/pk/pk-magic/scalar-
// magic/SGPR-x) with naive costs 3..7 inst/elem all timed 142.6 +/- 0.6 --
// too perfect; hypothesis: clang canonicalizes them to the SAME machine code
// (source never reached the ISA). R11's amplified pk variant: 135us,
// VALUBusy 77%, FETCH 214MB.
// Pre-committed readout:
//   ~135us & VALUBusy>=70% -> canonicalization confirmed, issue-bound at
//       ~7/elem -> R15: inline-asm dot (forced 3/elem, uncanonicalizable);
//   ~135us & VALUBusy<=45% -> scalar code IS different & stall-bound ->
//       read FETCH/WRITE, attack stalls;
//   75-95us -> lean dot + concurrency interact; re-model.
// History: latency/TLP dead (R1,R3,R11); balance dead (R6); memory dead
//   (R10 T_hot==T_cold, R11 27% HBM); fences toxic (R8); coop fails (R7);
//   dot restructures x5 neutral (R0/R4/R5/R12/R13).

constexpr int O_FEAT  = 28672;
constexpr int IN_FEAT = 8192;
constexpr int NGROUP  = IN_FEAT / 32;   // 256 groups (3 packed int32 rows each)
constexpr int SPLIT   = 32;             // split-K factor
constexpr int GPB     = NGROUP / SPLIT; // 8 groups per thread
constexpr int O4      = O_FEAT / 4;     // uint4 columns per packed row
constexpr int NBX     = O4 / 64;        // 112 column groups (256 cols each)
constexpr int NREP    = 5;              // amplification layers (z)

// 3-bit field at bit sh of w -> float(2 + c/4): shift field into mantissa
// bits [20:23) of 2.0f (ULP of [2,4) is 2^-22; c<<20 = c/4).
__device__ __forceinline__ float mg2(uint32_t w, int sh) {
  uint32_t u = (sh < 20) ? ((w << (20 - sh)) & 0x00700000u)
                         : ((w >> (sh - 20)) & 0x00700000u);
  return __uint_as_float(u | 0x40000000u);
}

// Unpack one column-group (32 3-bit codes in w0,w1,w2; GPTQ packing) and
// accumulate dot with uniform xv. 3 VALU/element target; 3 chains/column.
__device__ __forceinline__ void dot_group_sg(uint32_t w0, uint32_t w1, uint32_t w2,
                                             const float xv[32], float& acc) {
  float a0 = acc, a1 = 0.f, a2 = 0.f;
  #pragma unroll
  for (int j = 0; j < 10; ++j) a0 = fmaf(xv[j], mg2(w0, 3 * j), a0);
  { // e10 = (w0>>30)|((w1&1)<<2)
    uint32_t u = (((w0 >> 10) & 0x00300000u) | 0x40000000u) | ((w1 << 22) & 0x00400000u);
    a0 = fmaf(xv[10], __uint_as_float(u), a0);
  }
  #pragma unroll
  for (int j = 0; j < 10; ++j) a1 = fmaf(xv[11 + j], mg2(w1, 3 * j + 1), a1);
  { // e21 = (w1>>31)|((w2&3)<<1)
    uint32_t u = (((w1 >> 11) & 0x00100000u) | 0x40000000u) | ((w2 << 21) & 0x00600000u);
    a1 = fmaf(xv[21], __uint_as_float(u), a1);
  }
  #pragma unroll
  for (int j = 0; j < 10; ++j) a2 = fmaf(xv[22 + j], mg2(w2, 3 * j + 2), a2);
  acc = a0 + (a1 + a2);
}

__global__ __launch_bounds__(64) void q3_onepass(const float* __restrict__ x,
                                                 const uint4* __restrict__ qw4,
                                                 const float* __restrict__ scales,
                                                 const float* __restrict__ zeros,
                                                 const float* __restrict__ bias,
                                                 float* __restrict__ out,
                                                 float* __restrict__ dummy) {
  const int tcol4 = blockIdx.x * 64 + threadIdx.x;   // index in units of 4 columns
  const int g0    = blockIdx.y * GPB;
  const uint4* qp = qw4 + (size_t)(3 * g0) * O4 + tcol4;
  const float* xb = x + g0 * 32;                     // block-uniform

  float acc0 = 0.f, acc1 = 0.f, acc2 = 0.f, acc3 = 0.f;

  // Rolled loop, depth-1 qweight prefetch (last iter re-loads own rows: L1 hit).
  uint4 na = qp[0], nb = qp[O4], nc = qp[2 * O4];
  for (int g = 0; g < GPB; ++g) {
    const uint4 wa = na, wb = nb, wc = nc;
    qp += (g < GPB - 1) ? 3 * O4 : 0;
    na = qp[0]; nb = qp[O4]; nc = qp[2 * O4];

    // 32 wave-uniform x values (uniform-address loads -> SMEM path).
    float xv[32];
    #pragma unroll
    for (int j = 0; j < 32; ++j) xv[j] = xb[g * 32 + j];

    dot_group_sg(wa.x, wb.x, wc.x, xv, acc0);  // 4 cols x 3 chains = 12-deep ILP
    dot_group_sg(wa.y, wb.y, wc.y, xv, acc1);
    dot_group_sg(wa.z, wb.z, wc.z, xv, acc2);
    dot_group_sg(wa.w, wb.w, wc.w, xv, acc3);
  }

  // acc = 2*S_range + dot_range/4 per column -> multiply by 4*scales here;
  // the 8*scales*S magic bias is cancelled in the by==0 correction below.
  const float4 sc = reinterpret_cast<const float4*>(scales)[tcol4];
  float4 contrib;
  contrib.x = 4.f * sc.x * acc0;
  contrib.y = 4.f * sc.y * acc1;
  contrib.z = 4.f * sc.z * acc2;
  contrib.w = 4.f * sc.w * acc3;

  if (blockIdx.y == 0) {
    // Fold in bias - (8*scales + zeros) * S.
    float s = 0.f;
    const float4* xall = reinterpret_cast<const float4*>(x);
    #pragma unroll
    for (int i = 0; i < (IN_FEAT / 4) / 64; ++i) {   // 32 float4 per lane
      float4 t = xall[i * 64 + threadIdx.x];
      s += (t.x + t.y) + (t.z + t.w);
    }
    #pragma unroll
    for (int off = 32; off > 0; off >>= 1) s += __shfl_xor(s, off, 64);
    const float S = s;                               // all lanes hold the total
    const float4 zr = reinterpret_cast<const float4*>(zeros)[tcol4];
    const float4 bi = reinterpret_cast<const float4*>(bias)[tcol4];
    contrib.x += bi.x - (8.f * sc.x + zr.x) * S;
    contrib.y += bi.y - (8.f * sc.y + zr.y) * S;
    contrib.z += bi.z - (8.f * sc.z + zr.z) * S;
    contrib.w += bi.w - (8.f * sc.w + zr.w) * S;
  }

  // z layers 0..3 -> dummy regions (measurement amplification); z==4 -> out.
  float* target = (blockIdx.z == NREP - 1)
                    ? out
                    : dummy + (size_t)blockIdx.z * O_FEAT;
  float* op = target + 4 * (size_t)tcol4;
  atomicAdd(op + 0, contrib.x);
  atomicAdd(op + 1, contrib.y);
  atomicAdd(op + 2, contrib.z);
  atomicAdd(op + 3, contrib.w);
}

extern "C" void kernel_launch(void* const* d_in, const int* in_sizes, int n_in,
                              void* d_out, int out_size, void* d_ws, size_t ws_size,
                              hipStream_t stream) {
  const float* x      = (const float*)d_in[0];
  const uint4* qw4    = (const uint4*)d_in[1];
  const float* scales = (const float*)d_in[2];
  const float* zeros  = (const float*)d_in[3];
  const float* bias   = (const float*)d_in[4];
  float*       out    = (float*)d_out;
  float*       dummy  = (float*)d_ws;   // 4 * O_FEAT floats = 448 KB scratch

  q3_onepass<<<dim3(NBX, SPLIT, NREP), dim3(64), 0, stream>>>(
      x, qw4, scales, zeros, bias, out, dummy);
}

// Round 15
// 145.770 us; speedup vs baseline: 1.5932x; 1.5932x over previous
//
#include <hip/hip_runtime.h>
#include <stdint.h>

// Quant3Linear GEMV: y = x @ (scales.T * unpack3(qweight) - zeros.T) + bias
//   x: (1, 8192) f32 | qweight: (768, 28672) i32 | scales,zeros: (28672,1) | bias: (28672,)
// Decomposition: y[o] = scales[o]*dot(x, q[:,o]) - zeros[o]*sum(x) + bias[o]
//
// R15: INLINE-ASM DOT. R11+R14 amplified counters proved all five HIP-source
// dot variants canonicalize to the SAME ~7.4 emitted insts/element (VALUBusy
// 77-79%, issue-bound). This kernel forces exactly 3 VALU/element in asm:
//   v_lshlrev_b32 t, imm, w           (field -> mantissa bits [20:23))
//   v_and_or_b32  t, t, sMask, 2.0    (SGPR mask + INLINE 2.0 base: 2 + c/4)
//   v_fmac_f32    acc, x, t
// One asm block per element covers 4 columns (12 insts, deps 4 apart).
// Split codes e10/e21: 5 insts/col. e28 (sh==20): shift-free, 2/elem.
// x in LDS (lgkm path; vmcnt stays qweight-only w/ depth-1 prefetch).
// Algebra (R13-validated): acc = 2*S_range + dot/4;
//   y = 4*sc*acc - (8*sc + zr)*S + bias. Fence-free atomic epilogue (R9).
// History: latency/TLP dead (R1,R3,R11); balance dead (R6); memory dead
//   (R10 T_hot==T_cold, R11/R14 ~26% HBM); fences toxic (R8); coop fails
//   (R7); HIP-source dot edits canonicalized away x5 (R0/R4/R5/R12/R13).

constexpr int O_FEAT  = 28672;
constexpr int IN_FEAT = 8192;
constexpr int NGROUP  = IN_FEAT / 32;   // 256 groups (3 packed int32 rows each)
constexpr int SPLIT   = 32;             // split-K factor
constexpr int GPB     = NGROUP / SPLIT; // 8 groups per thread
constexpr int O4      = O_FEAT / 4;     // uint4 columns per packed row
constexpr int NBX     = O4 / 64;        // 112 column groups (256 cols each)

// One regular element (field at bit SH of per-column word) for 4 columns.
template <int SH>
__device__ __forceinline__ void q3e4(uint32_t va, uint32_t vb, uint32_t vc, uint32_t vd,
                                     uint32_t m7, float xj,
                                     float& A, float& B, float& C, float& D) {
  float t0, t1, t2, t3;
  if constexpr (SH < 20) {
    asm("v_lshlrev_b32 %0, %12, %8\n\t"
        "v_lshlrev_b32 %1, %12, %9\n\t"
        "v_lshlrev_b32 %2, %12, %10\n\t"
        "v_lshlrev_b32 %3, %12, %11\n\t"
        "v_and_or_b32 %0, %0, %13, 2.0\n\t"
        "v_and_or_b32 %1, %1, %13, 2.0\n\t"
        "v_and_or_b32 %2, %2, %13, 2.0\n\t"
        "v_and_or_b32 %3, %3, %13, 2.0\n\t"
        "v_fmac_f32 %4, %14, %0\n\t"
        "v_fmac_f32 %5, %14, %1\n\t"
        "v_fmac_f32 %6, %14, %2\n\t"
        "v_fmac_f32 %7, %14, %3"
        : "=&v"(t0), "=&v"(t1), "=&v"(t2), "=&v"(t3),
          "+v"(A), "+v"(B), "+v"(C), "+v"(D)
        : "v"(va), "v"(vb), "v"(vc), "v"(vd), "n"(20 - SH), "s"(m7), "v"(xj));
  } else if constexpr (SH == 20) {
    asm("v_and_or_b32 %0, %8, %12, 2.0\n\t"
        "v_and_or_b32 %1, %9, %12, 2.0\n\t"
        "v_and_or_b32 %2, %10, %12, 2.0\n\t"
        "v_and_or_b32 %3, %11, %12, 2.0\n\t"
        "v_fmac_f32 %4, %13, %0\n\t"
        "v_fmac_f32 %5, %13, %1\n\t"
        "v_fmac_f32 %6, %13, %2\n\t"
        "v_fmac_f32 %7, %13, %3"
        : "=&v"(t0), "=&v"(t1), "=&v"(t2), "=&v"(t3),
          "+v"(A), "+v"(B), "+v"(C), "+v"(D)
        : "v"(va), "v"(vb), "v"(vc), "v"(vd), "s"(m7), "v"(xj));
  } else {
    asm("v_lshrrev_b32 %0, %12, %8\n\t"
        "v_lshrrev_b32 %1, %12, %9\n\t"
        "v_lshrrev_b32 %2, %12, %10\n\t"
        "v_lshrrev_b32 %3, %12, %11\n\t"
        "v_and_or_b32 %0, %0, %13, 2.0\n\t"
        "v_and_or_b32 %1, %1, %13, 2.0\n\t"
        "v_and_or_b32 %2, %2, %13, 2.0\n\t"
        "v_and_or_b32 %3, %3, %13, 2.0\n\t"
        "v_fmac_f32 %4, %14, %0\n\t"
        "v_fmac_f32 %5, %14, %1\n\t"
        "v_fmac_f32 %6, %14, %2\n\t"
        "v_fmac_f32 %7, %14, %3"
        : "=&v"(t0), "=&v"(t1), "=&v"(t2), "=&v"(t3),
          "+v"(A), "+v"(B), "+v"(C), "+v"(D)
        : "v"(va), "v"(vb), "v"(vc), "v"(vd), "n"(SH - 20), "s"(m7), "v"(xj));
  }
}

// e10 = (w0>>30)|((w1&1)<<2): u = ((w0>>10)&0x300000)|((w1<<22)&0x400000)|2.0
__device__ __forceinline__ void q3e4_s10(uint4 wa, uint4 wb, uint32_t m3, uint32_t m4,
                                         float xj, float& A, float& B, float& C, float& D) {
  float t0, t1, t2, t3, u0, u1, u2, u3;
  asm("v_lshrrev_b32 %0, 10, %12\n\t"
      "v_lshrrev_b32 %1, 10, %13\n\t"
      "v_lshrrev_b32 %2, 10, %14\n\t"
      "v_lshrrev_b32 %3, 10, %15\n\t"
      "v_lshlrev_b32 %4, 22, %16\n\t"
      "v_lshlrev_b32 %5, 22, %17\n\t"
      "v_lshlrev_b32 %6, 22, %18\n\t"
      "v_lshlrev_b32 %7, 22, %19\n\t"
      "v_and_or_b32 %0, %0, %20, 2.0\n\t"
      "v_and_or_b32 %1, %1, %20, 2.0\n\t"
      "v_and_or_b32 %2, %2, %20, 2.0\n\t"
      "v_and_or_b32 %3, %3, %20, 2.0\n\t"
      "v_and_or_b32 %0, %4, %21, %0\n\t"
      "v_and_or_b32 %1, %5, %21, %1\n\t"
      "v_and_or_b32 %2, %6, %21, %2\n\t"
      "v_and_or_b32 %3, %7, %21, %3\n\t"
      "v_fmac_f32 %8, %22, %0\n\t"
      "v_fmac_f32 %9, %22, %1\n\t"
      "v_fmac_f32 %10, %22, %2\n\t"
      "v_fmac_f32 %11, %22, %3"
      : "=&v"(t0), "=&v"(t1), "=&v"(t2), "=&v"(t3),
        "=&v"(u0), "=&v"(u1), "=&v"(u2), "=&v"(u3),
        "+v"(A), "+v"(B), "+v"(C), "+v"(D)
      : "v"(wa.x), "v"(wa.y), "v"(wa.z), "v"(wa.w),
        "v"(wb.x), "v"(wb.y), "v"(wb.z), "v"(wb.w),
        "s"(m3), "s"(m4), "v"(xj));
}

// e21 = (w1>>31)|((w2&3)<<1): u = ((w1>>11)&0x100000)|((w2<<21)&0x600000)|2.0
__device__ __forceinline__ void q3e4_s21(uint4 wb, uint4 wc, uint32_t m1, uint32_t m6,
                                         float xj, float& A, float& B, float& C, float& D) {
  float t0, t1, t2, t3, u0, u1, u2, u3;
  asm("v_lshrrev_b32 %0, 11, %12\n\t"
      "v_lshrrev_b32 %1, 11, %13\n\t"
      "v_lshrrev_b32 %2, 11, %14\n\t"
      "v_lshrrev_b32 %3, 11, %15\n\t"
      "v_lshlrev_b32 %4, 21, %16\n\t"
      "v_lshlrev_b32 %5, 21, %17\n\t"
      "v_lshlrev_b32 %6, 21, %18\n\t"
      "v_lshlrev_b32 %7, 21, %19\n\t"
      "v_and_or_b32 %0, %0, %20, 2.0\n\t"
      "v_and_or_b32 %1, %1, %20, 2.0\n\t"
      "v_and_or_b32 %2, %2, %20, 2.0\n\t"
      "v_and_or_b32 %3, %3, %20, 2.0\n\t"
      "v_and_or_b32 %0, %4, %21, %0\n\t"
      "v_and_or_b32 %1, %5, %21, %1\n\t"
      "v_and_or_b32 %2, %6, %21, %2\n\t"
      "v_and_or_b32 %3, %7, %21, %3\n\t"
      "v_fmac_f32 %8, %22, %0\n\t"
      "v_fmac_f32 %9, %22, %1\n\t"
      "v_fmac_f32 %10, %22, %2\n\t"
      "v_fmac_f32 %11, %22, %3"
      : "=&v"(t0), "=&v"(t1), "=&v"(t2), "=&v"(t3),
        "=&v"(u0), "=&v"(u1), "=&v"(u2), "=&v"(u3),
        "+v"(A), "+v"(B), "+v"(C), "+v"(D)
      : "v"(wb.x), "v"(wb.y), "v"(wb.z), "v"(wb.w),
        "v"(wc.x), "v"(wc.y), "v"(wc.z), "v"(wc.w),
        "s"(m1), "s"(m6), "v"(xj));
}

__global__ __launch_bounds__(64) void q3_onepass(const float* __restrict__ x,
                                                 const uint4* __restrict__ qw4,
                                                 const float* __restrict__ scales,
                                                 const float* __restrict__ zeros,
                                                 const float* __restrict__ bias,
                                                 float* __restrict__ out) {
  const int tcol4 = blockIdx.x * 64 + threadIdx.x;   // index in units of 4 columns
  const int g0    = blockIdx.y * GPB;
  const uint4* qp = qw4 + (size_t)(3 * g0) * O4 + tcol4;

  // Stage this block's x chunk (256 floats = 1 KB, RAW) in LDS: one
  // float4/thread; single wave -> no barrier (lgkmcnt orders).
  __shared__ float xs[GPB * 32];
  const float4 xt = reinterpret_cast<const float4*>(x + g0 * 32)[threadIdx.x];
  reinterpret_cast<float4*>(xs)[threadIdx.x] = xt;

  const uint32_t m7 = 0x00700000u, m3 = 0x00300000u, m4 = 0x00400000u,
                 m1 = 0x00100000u, m6 = 0x00600000u;

  float A = 0.f, B = 0.f, C = 0.f, D = 0.f;   // 4 column accumulators

  // Rolled loop, depth-1 qweight prefetch (last iter re-loads own rows: L1 hit).
  uint4 na = qp[0], nb = qp[O4], nc = qp[2 * O4];
  for (int g = 0; g < GPB; ++g) {
    const uint4 wa = na, wb = nb, wc = nc;
    qp += (g < GPB - 1) ? 3 * O4 : 0;
    na = qp[0]; nb = qp[O4]; nc = qp[2 * O4];

    float xv[32];
    const float4* s4 = reinterpret_cast<const float4*>(&xs[g * 32]);
    #pragma unroll
    for (int u = 0; u < 8; ++u) {
      float4 t = s4[u];
      xv[4 * u + 0] = t.x; xv[4 * u + 1] = t.y;
      xv[4 * u + 2] = t.z; xv[4 * u + 3] = t.w;
    }

    // word0: e0..e9 at sh=3j
    q3e4<0>(wa.x, wa.y, wa.z, wa.w, m7, xv[0], A, B, C, D);
    q3e4<3>(wa.x, wa.y, wa.z, wa.w, m7, xv[1], A, B, C, D);
    q3e4<6>(wa.x, wa.y, wa.z, wa.w, m7, xv[2], A, B, C, D);
    q3e4<9>(wa.x, wa.y, wa.z, wa.w, m7, xv[3], A, B, C, D);
    q3e4<12>(wa.x, wa.y, wa.z, wa.w, m7, xv[4], A, B, C, D);
    q3e4<15>(wa.x, wa.y, wa.z, wa.w, m7, xv[5], A, B, C, D);
    q3e4<18>(wa.x, wa.y, wa.z, wa.w, m7, xv[6], A, B, C, D);
    q3e4<21>(wa.x, wa.y, wa.z, wa.w, m7, xv[7], A, B, C, D);
    q3e4<24>(wa.x, wa.y, wa.z, wa.w, m7, xv[8], A, B, C, D);
    q3e4<27>(wa.x, wa.y, wa.z, wa.w, m7, xv[9], A, B, C, D);
    // e10 split w0/w1
    q3e4_s10(wa, wb, m3, m4, xv[10], A, B, C, D);
    // word1: e11..e20 at sh=3j+1
    q3e4<1>(wb.x, wb.y, wb.z, wb.w, m7, xv[11], A, B, C, D);
    q3e4<4>(wb.x, wb.y, wb.z, wb.w, m7, xv[12], A, B, C, D);
    q3e4<7>(wb.x, wb.y, wb.z, wb.w, m7, xv[13], A, B, C, D);
    q3e4<10>(wb.x, wb.y, wb.z, wb.w, m7, xv[14], A, B, C, D);
    q3e4<13>(wb.x, wb.y, wb.z, wb.w, m7, xv[15], A, B, C, D);
    q3e4<16>(wb.x, wb.y, wb.z, wb.w, m7, xv[16], A, B, C, D);
    q3e4<19>(wb.x, wb.y, wb.z, wb.w, m7, xv[17], A, B, C, D);
    q3e4<22>(wb.x, wb.y, wb.z, wb.w, m7, xv[18], A, B, C, D);
    q3e4<25>(wb.x, wb.y, wb.z, wb.w, m7, xv[19], A, B, C, D);
    q3e4<28>(wb.x, wb.y, wb.z, wb.w, m7, xv[20], A, B, C, D);
    // e21 split w1/w2
    q3e4_s21(wb, wc, m1, m6, xv[21], A, B, C, D);
    // word2: e22..e31 at sh=3j+2
    q3e4<2>(wc.x, wc.y, wc.z, wc.w, m7, xv[22], A, B, C, D);
    q3e4<5>(wc.x, wc.y, wc.z, wc.w, m7, xv[23], A, B, C, D);
    q3e4<8>(wc.x, wc.y, wc.z, wc.w, m7, xv[24], A, B, C, D);
    q3e4<11>(wc.x, wc.y, wc.z, wc.w, m7, xv[25], A, B, C, D);
    q3e4<14>(wc.x, wc.y, wc.z, wc.w, m7, xv[26], A, B, C, D);
    q3e4<17>(wc.x, wc.y, wc.z, wc.w, m7, xv[27], A, B, C, D);
    q3e4<20>(wc.x, wc.y, wc.z, wc.w, m7, xv[28], A, B, C, D);
    q3e4<23>(wc.x, wc.y, wc.z, wc.w, m7, xv[29], A, B, C, D);
    q3e4<26>(wc.x, wc.y, wc.z, wc.w, m7, xv[30], A, B, C, D);
    q3e4<29>(wc.x, wc.y, wc.z, wc.w, m7, xv[31], A, B, C, D);
  }

  // acc = 2*S_range + dot_range/4 per column -> 4*scales * acc here;
  // the 8*scales*S magic bias is cancelled in the by==0 correction below.
  const float4 sc = reinterpret_cast<const float4*>(scales)[tcol4];
  float4 contrib;
  contrib.x = 4.f * sc.x * A;
  contrib.y = 4.f * sc.y * B;
  contrib.z = 4.f * sc.z * C;
  contrib.w = 4.f * sc.w * D;

  if (blockIdx.y == 0) {
    // Fold in bias - (8*scales + zeros) * S.
    float s = 0.f;
    const float4* xall = reinterpret_cast<const float4*>(x);
    #pragma unroll
    for (int i = 0; i < (IN_FEAT / 4) / 64; ++i) {   // 32 float4 per lane
      float4 t = xall[i * 64 + threadIdx.x];
      s += (t.x + t.y) + (t.z + t.w);
    }
    #pragma unroll
    for (int off = 32; off > 0; off >>= 1) s += __shfl_xor(s, off, 64);
    const float S = s;                               // all lanes hold the total
    const float4 zr = reinterpret_cast<const float4*>(zeros)[tcol4];
    const float4 bi = reinterpret_cast<const float4*>(bias)[tcol4];
    contrib.x += bi.x - (8.f * sc.x + zr.x) * S;
    contrib.y += bi.y - (8.f * sc.y + zr.y) * S;
    contrib.z += bi.z - (8.f * sc.z + zr.z) * S;
    contrib.w += bi.w - (8.f * sc.w + zr.w) * S;
  }

  float* op = out + 4 * (size_t)tcol4;
  atomicAdd(op + 0, contrib.x);
  atomicAdd(op + 1, contrib.y);
  atomicAdd(op + 2, contrib.z);
  atomicAdd(op + 3, contrib.w);
}

extern "C" void kernel_launch(void* const* d_in, const int* in_sizes, int n_in,
                              void* d_out, int out_size, void* d_ws, size_t ws_size,
                              hipStream_t stream) {
  const float* x      = (const float*)d_in[0];
  const uint4* qw4    = (const uint4*)d_in[1];
  const float* scales = (const float*)d_in[2];
  const float* zeros  = (const float*)d_in[3];
  const float* bias   = (const float*)d_in[4];
  float*       out    = (float*)d_out;

  q3_onepass<<<dim3(NBX, SPLIT), dim3(64), 0, stream>>>(x, qw4, scales, zeros,
                                                        bias, out);
}

// Round 16
// 138.692 us; speedup vs baseline: 1.6745x; 1.0510x over previous
//
#include <hip/hip_runtime.h>
#include <stdint.h>

// Quant3Linear GEMV: y = x @ (scales.T * unpack3(qweight) - zeros.T) + bias
//   x: (1, 8192) f32 | qweight: (768, 28672) i32 | scales,zeros: (28672,1) | bias: (28672,)
// Decomposition: y[o] = scales[o]*dot(x, q[:,o]) - zeros[o]*sum(x) + bias[o]
//
// R16: DEPTH-2 SLIDING-WINDOW PREFETCH (counted-vmcnt pattern). R15 proved
// the time is invariant to VALU inst count (asm 3.2/elem == HIP 7.4/elem,
// absmax shift proves the asm ran) -> not issue-bound. Back-computed ~1900
// cycles per group-iteration = serialized load latency: the old depth-1
// "prefetch" (na->wa copy) canonicalizes to load;vmcnt(0);compute per group.
// Fix: fully-unrolled w[8][3] window, issue group g+2's 3 loads BEFORE
// computing group g -> consumption order == issue order -> clang emits
// vmcnt(~6), never 0 mid-loop; latency overlaps compute across iterations.
// Compute: R15's inline-asm dot (3 VALU/elem: lshl, and_or(2.0 base), fmac;
// value = 2 + c/4; y = 4*sc*acc - (8*sc+zr)*S + bias). Fence-free atomic
// epilogue (R9). 3584 x 1-wave blocks.
// History: issue dead (R15); TLP dead (R1,R11); balance dead (R6); memory
//   dead (R10 hot==cold); fences toxic (R8); coop fails (R7); dispatch
//   count neutral (R9); dot rewrites canonicalized x5 (R0,R4,R5,R12,R13).

constexpr int O_FEAT  = 28672;
constexpr int IN_FEAT = 8192;
constexpr int NGROUP  = IN_FEAT / 32;   // 256 groups (3 packed int32 rows each)
constexpr int SPLIT   = 32;             // split-K factor
constexpr int GPB     = NGROUP / SPLIT; // 8 groups per thread
constexpr int O4      = O_FEAT / 4;     // uint4 columns per packed row
constexpr int NBX     = O4 / 64;        // 112 column groups (256 cols each)

// One regular element (field at bit SH of per-column word) for 4 columns.
template <int SH>
__device__ __forceinline__ void q3e4(uint32_t va, uint32_t vb, uint32_t vc, uint32_t vd,
                                     uint32_t m7, float xj,
                                     float& A, float& B, float& C, float& D) {
  float t0, t1, t2, t3;
  if constexpr (SH < 20) {
    asm("v_lshlrev_b32 %0, %12, %8\n\t"
        "v_lshlrev_b32 %1, %12, %9\n\t"
        "v_lshlrev_b32 %2, %12, %10\n\t"
        "v_lshlrev_b32 %3, %12, %11\n\t"
        "v_and_or_b32 %0, %0, %13, 2.0\n\t"
        "v_and_or_b32 %1, %1, %13, 2.0\n\t"
        "v_and_or_b32 %2, %2, %13, 2.0\n\t"
        "v_and_or_b32 %3, %3, %13, 2.0\n\t"
        "v_fmac_f32 %4, %14, %0\n\t"
        "v_fmac_f32 %5, %14, %1\n\t"
        "v_fmac_f32 %6, %14, %2\n\t"
        "v_fmac_f32 %7, %14, %3"
        : "=&v"(t0), "=&v"(t1), "=&v"(t2), "=&v"(t3),
          "+v"(A), "+v"(B), "+v"(C), "+v"(D)
        : "v"(va), "v"(vb), "v"(vc), "v"(vd), "n"(20 - SH), "s"(m7), "v"(xj));
  } else if constexpr (SH == 20) {
    asm("v_and_or_b32 %0, %8, %12, 2.0\n\t"
        "v_and_or_b32 %1, %9, %12, 2.0\n\t"
        "v_and_or_b32 %2, %10, %12, 2.0\n\t"
        "v_and_or_b32 %3, %11, %12, 2.0\n\t"
        "v_fmac_f32 %4, %13, %0\n\t"
        "v_fmac_f32 %5, %13, %1\n\t"
        "v_fmac_f32 %6, %13, %2\n\t"
        "v_fmac_f32 %7, %13, %3"
        : "=&v"(t0), "=&v"(t1), "=&v"(t2), "=&v"(t3),
          "+v"(A), "+v"(B), "+v"(C), "+v"(D)
        : "v"(va), "v"(vb), "v"(vc), "v"(vd), "s"(m7), "v"(xj));
  } else {
    asm("v_lshrrev_b32 %0, %12, %8\n\t"
        "v_lshrrev_b32 %1, %12, %9\n\t"
        "v_lshrrev_b32 %2, %12, %10\n\t"
        "v_lshrrev_b32 %3, %12, %11\n\t"
        "v_and_or_b32 %0, %0, %13, 2.0\n\t"
        "v_and_or_b32 %1, %1, %13, 2.0\n\t"
        "v_and_or_b32 %2, %2, %13, 2.0\n\t"
        "v_and_or_b32 %3, %3, %13, 2.0\n\t"
        "v_fmac_f32 %4, %14, %0\n\t"
        "v_fmac_f32 %5, %14, %1\n\t"
        "v_fmac_f32 %6, %14, %2\n\t"
        "v_fmac_f32 %7, %14, %3"
        : "=&v"(t0), "=&v"(t1), "=&v"(t2), "=&v"(t3),
          "+v"(A), "+v"(B), "+v"(C), "+v"(D)
        : "v"(va), "v"(vb), "v"(vc), "v"(vd), "n"(SH - 20), "s"(m7), "v"(xj));
  }
}

// e10 = (w0>>30)|((w1&1)<<2): u = ((w0>>10)&0x300000)|((w1<<22)&0x400000)|2.0
__device__ __forceinline__ void q3e4_s10(uint4 wa, uint4 wb, uint32_t m3, uint32_t m4,
                                         float xj, float& A, float& B, float& C, float& D) {
  float t0, t1, t2, t3, u0, u1, u2, u3;
  asm("v_lshrrev_b32 %0, 10, %12\n\t"
      "v_lshrrev_b32 %1, 10, %13\n\t"
      "v_lshrrev_b32 %2, 10, %14\n\t"
      "v_lshrrev_b32 %3, 10, %15\n\t"
      "v_lshlrev_b32 %4, 22, %16\n\t"
      "v_lshlrev_b32 %5, 22, %17\n\t"
      "v_lshlrev_b32 %6, 22, %18\n\t"
      "v_lshlrev_b32 %7, 22, %19\n\t"
      "v_and_or_b32 %0, %0, %20, 2.0\n\t"
      "v_and_or_b32 %1, %1, %20, 2.0\n\t"
      "v_and_or_b32 %2, %2, %20, 2.0\n\t"
      "v_and_or_b32 %3, %3, %20, 2.0\n\t"
      "v_and_or_b32 %0, %4, %21, %0\n\t"
      "v_and_or_b32 %1, %5, %21, %1\n\t"
      "v_and_or_b32 %2, %6, %21, %2\n\t"
      "v_and_or_b32 %3, %7, %21, %3\n\t"
      "v_fmac_f32 %8, %22, %0\n\t"
      "v_fmac_f32 %9, %22, %1\n\t"
      "v_fmac_f32 %10, %22, %2\n\t"
      "v_fmac_f32 %11, %22, %3"
      : "=&v"(t0), "=&v"(t1), "=&v"(t2), "=&v"(t3),
        "=&v"(u0), "=&v"(u1), "=&v"(u2), "=&v"(u3),
        "+v"(A), "+v"(B), "+v"(C), "+v"(D)
      : "v"(wa.x), "v"(wa.y), "v"(wa.z), "v"(wa.w),
        "v"(wb.x), "v"(wb.y), "v"(wb.z), "v"(wb.w),
        "s"(m3), "s"(m4), "v"(xj));
}

// e21 = (w1>>31)|((w2&3)<<1): u = ((w1>>11)&0x100000)|((w2<<21)&0x600000)|2.0
__device__ __forceinline__ void q3e4_s21(uint4 wb, uint4 wc, uint32_t m1, uint32_t m6,
                                         float xj, float& A, float& B, float& C, float& D) {
  float t0, t1, t2, t3, u0, u1, u2, u3;
  asm("v_lshrrev_b32 %0, 11, %12\n\t"
      "v_lshrrev_b32 %1, 11, %13\n\t"
      "v_lshrrev_b32 %2, 11, %14\n\t"
      "v_lshrrev_b32 %3, 11, %15\n\t"
      "v_lshlrev_b32 %4, 21, %16\n\t"
      "v_lshlrev_b32 %5, 21, %17\n\t"
      "v_lshlrev_b32 %6, 21, %18\n\t"
      "v_lshlrev_b32 %7, 21, %19\n\t"
      "v_and_or_b32 %0, %0, %20, 2.0\n\t"
      "v_and_or_b32 %1, %1, %20, 2.0\n\t"
      "v_and_or_b32 %2, %2, %20, 2.0\n\t"
      "v_and_or_b32 %3, %3, %20, 2.0\n\t"
      "v_and_or_b32 %0, %4, %21, %0\n\t"
      "v_and_or_b32 %1, %5, %21, %1\n\t"
      "v_and_or_b32 %2, %6, %21, %2\n\t"
      "v_and_or_b32 %3, %7, %21, %3\n\t"
      "v_fmac_f32 %8, %22, %0\n\t"
      "v_fmac_f32 %9, %22, %1\n\t"
      "v_fmac_f32 %10, %22, %2\n\t"
      "v_fmac_f32 %11, %22, %3"
      : "=&v"(t0), "=&v"(t1), "=&v"(t2), "=&v"(t3),
        "=&v"(u0), "=&v"(u1), "=&v"(u2), "=&v"(u3),
        "+v"(A), "+v"(B), "+v"(C), "+v"(D)
      : "v"(wb.x), "v"(wb.y), "v"(wb.z), "v"(wb.w),
        "v"(wc.x), "v"(wc.y), "v"(wc.z), "v"(wc.w),
        "s"(m1), "s"(m6), "v"(xj));
}

__global__ __launch_bounds__(64) void q3_onepass(const float* __restrict__ x,
                                                 const uint4* __restrict__ qw4,
                                                 const float* __restrict__ scales,
                                                 const float* __restrict__ zeros,
                                                 const float* __restrict__ bias,
                                                 float* __restrict__ out) {
  const int tcol4 = blockIdx.x * 64 + threadIdx.x;   // index in units of 4 columns
  const int g0    = blockIdx.y * GPB;
  const uint4* qp = qw4 + (size_t)(3 * g0) * O4 + tcol4;

  // Stage this block's x chunk (256 floats = 1 KB, raw) in LDS.
  __shared__ float xs[GPB * 32];
  const float4 xt = reinterpret_cast<const float4*>(x + g0 * 32)[threadIdx.x];
  reinterpret_cast<float4*>(xs)[threadIdx.x] = xt;

  const uint32_t m7 = 0x00700000u, m3 = 0x00300000u, m4 = 0x00400000u,
                 m1 = 0x00100000u, m6 = 0x00600000u;

  float A = 0.f, B = 0.f, C = 0.f, D = 0.f;   // 4 column accumulators

  // Depth-2 sliding window: w[g] filled 2 iterations ahead of use. All
  // indices compile-time (full unroll) -> registers; live window ~3 groups
  // (36 VGPR). Issue order == consumption order -> counted vmcnt, never 0.
  uint4 w[GPB][3];
  #pragma unroll
  for (int g = 0; g < 2; ++g) {
    w[g][0] = qp[0]; w[g][1] = qp[O4]; w[g][2] = qp[2 * O4];
    qp += 3 * O4;
  }

  #pragma unroll
  for (int g = 0; g < GPB; ++g) {
    if (g + 2 < GPB) {   // compile-time after unroll
      w[g + 2][0] = qp[0]; w[g + 2][1] = qp[O4]; w[g + 2][2] = qp[2 * O4];
      qp += 3 * O4;
    }
    const uint4 wa = w[g][0], wb = w[g][1], wc = w[g][2];

    float xv[32];
    const float4* s4 = reinterpret_cast<const float4*>(&xs[g * 32]);
    #pragma unroll
    for (int u = 0; u < 8; ++u) {
      float4 t = s4[u];
      xv[4 * u + 0] = t.x; xv[4 * u + 1] = t.y;
      xv[4 * u + 2] = t.z; xv[4 * u + 3] = t.w;
    }

    // word0: e0..e9 at sh=3j
    q3e4<0>(wa.x, wa.y, wa.z, wa.w, m7, xv[0], A, B, C, D);
    q3e4<3>(wa.x, wa.y, wa.z, wa.w, m7, xv[1], A, B, C, D);
    q3e4<6>(wa.x, wa.y, wa.z, wa.w, m7, xv[2], A, B, C, D);
    q3e4<9>(wa.x, wa.y, wa.z, wa.w, m7, xv[3], A, B, C, D);
    q3e4<12>(wa.x, wa.y, wa.z, wa.w, m7, xv[4], A, B, C, D);
    q3e4<15>(wa.x, wa.y, wa.z, wa.w, m7, xv[5], A, B, C, D);
    q3e4<18>(wa.x, wa.y, wa.z, wa.w, m7, xv[6], A, B, C, D);
    q3e4<21>(wa.x, wa.y, wa.z, wa.w, m7, xv[7], A, B, C, D);
    q3e4<24>(wa.x, wa.y, wa.z, wa.w, m7, xv[8], A, B, C, D);
    q3e4<27>(wa.x, wa.y, wa.z, wa.w, m7, xv[9], A, B, C, D);
    // e10 split w0/w1
    q3e4_s10(wa, wb, m3, m4, xv[10], A, B, C, D);
    // word1: e11..e20 at sh=3j+1
    q3e4<1>(wb.x, wb.y, wb.z, wb.w, m7, xv[11], A, B, C, D);
    q3e4<4>(wb.x, wb.y, wb.z, wb.w, m7, xv[12], A, B, C, D);
    q3e4<7>(wb.x, wb.y, wb.z, wb.w, m7, xv[13], A, B, C, D);
    q3e4<10>(wb.x, wb.y, wb.z, wb.w, m7, xv[14], A, B, C, D);
    q3e4<13>(wb.x, wb.y, wb.z, wb.w, m7, xv[15], A, B, C, D);
    q3e4<16>(wb.x, wb.y, wb.z, wb.w, m7, xv[16], A, B, C, D);
    q3e4<19>(wb.x, wb.y, wb.z, wb.w, m7, xv[17], A, B, C, D);
    q3e4<22>(wb.x, wb.y, wb.z, wb.w, m7, xv[18], A, B, C, D);
    q3e4<25>(wb.x, wb.y, wb.z, wb.w, m7, xv[19], A, B, C, D);
    q3e4<28>(wb.x, wb.y, wb.z, wb.w, m7, xv[20], A, B, C, D);
    // e21 split w1/w2
    q3e4_s21(wb, wc, m1, m6, xv[21], A, B, C, D);
    // word2: e22..e31 at sh=3j+2
    q3e4<2>(wc.x, wc.y, wc.z, wc.w, m7, xv[22], A, B, C, D);
    q3e4<5>(wc.x, wc.y, wc.z, wc.w, m7, xv[23], A, B, C, D);
    q3e4<8>(wc.x, wc.y, wc.z, wc.w, m7, xv[24], A, B, C, D);
    q3e4<11>(wc.x, wc.y, wc.z, wc.w, m7, xv[25], A, B, C, D);
    q3e4<14>(wc.x, wc.y, wc.z, wc.w, m7, xv[26], A, B, C, D);
    q3e4<17>(wc.x, wc.y, wc.z, wc.w, m7, xv[27], A, B, C, D);
    q3e4<20>(wc.x, wc.y, wc.z, wc.w, m7, xv[28], A, B, C, D);
    q3e4<23>(wc.x, wc.y, wc.z, wc.w, m7, xv[29], A, B, C, D);
    q3e4<26>(wc.x, wc.y, wc.z, wc.w, m7, xv[30], A, B, C, D);
    q3e4<29>(wc.x, wc.y, wc.z, wc.w, m7, xv[31], A, B, C, D);
  }

  // acc = 2*S_range + dot_range/4 per column -> 4*scales * acc here;
  // the 8*scales*S magic bias is cancelled in the by==0 correction below.
  const float4 sc = reinterpret_cast<const float4*>(scales)[tcol4];
  float4 contrib;
  contrib.x = 4.f * sc.x * A;
  contrib.y = 4.f * sc.y * B;
  contrib.z = 4.f * sc.z * C;
  contrib.w = 4.f * sc.w * D;

  if (blockIdx.y == 0) {
    // Fold in bias - (8*scales + zeros) * S.
    float s = 0.f;
    const float4* xall = reinterpret_cast<const float4*>(x);
    #pragma unroll
    for (int i = 0; i < (IN_FEAT / 4) / 64; ++i) {   // 32 float4 per lane
      float4 t = xall[i * 64 + threadIdx.x];
      s += (t.x + t.y) + (t.z + t.w);
    }
    #pragma unroll
    for (int off = 32; off > 0; off >>= 1) s += __shfl_xor(s, off, 64);
    const float S = s;                               // all lanes hold the total
    const float4 zr = reinterpret_cast<const float4*>(zeros)[tcol4];
    const float4 bi = reinterpret_cast<const float4*>(bias)[tcol4];
    contrib.x += bi.x - (8.f * sc.x + zr.x) * S;
    contrib.y += bi.y - (8.f * sc.y + zr.y) * S;
    contrib.z += bi.z - (8.f * sc.z + zr.z) * S;
    contrib.w += bi.w - (8.f * sc.w + zr.w) * S;
  }

  float* op = out + 4 * (size_t)tcol4;
  atomicAdd(op + 0, contrib.x);
  atomicAdd(op + 1, contrib.y);
  atomicAdd(op + 2, contrib.z);
  atomicAdd(op + 3, contrib.w);
}

extern "C" void kernel_launch(void* const* d_in, const int* in_sizes, int n_in,
                              void* d_out, int out_size, void* d_ws, size_t ws_size,
                              hipStream_t stream) {
  const float* x      = (const float*)d_in[0];
  const uint4* qw4    = (const uint4*)d_in[1];
  const float* scales = (const float*)d_in[2];
  const float* zeros  = (const float*)d_in[3];
  const float* bias   = (const float*)d_in[4];
  float*       out    = (float*)d_out;

  q3_onepass<<<dim3(NBX, SPLIT), dim3(64), 0, stream>>>(x, qw4, scales, zeros,
                                                        bias, out);
}